// Round 2
// baseline (247.485 us; speedup 1.0000x reference)
//
#include <hip/hip_runtime.h>

// Problem constants (from reference)
#define T_DIM   64
#define N_DIM   128
#define M_TOT   (T_DIM * N_DIM)     // 8192
#define BATCH   2
#define F_IN    32
#define HIDW    32
#define F_OUT   16
#define NLAYER  2
#define KORD    4

// h state per batch: M_TOT * HIDW = 262144 floats
#define HSTATE  (M_TOT * HIDW)

// ---------------------------------------------------------------------------
// Kernel 1: h = x @ W1 + b1.  [16384 x 32] @ [32 x 32]
// block = 256 threads -> 8 rows/block; grid = 16384/8 = 2048
// ---------------------------------------------------------------------------
__global__ __launch_bounds__(256) void k_proj_in(
    const float* __restrict__ x, const float* __restrict__ W1,
    const float* __restrict__ b1, float* __restrict__ h)
{
    __shared__ float Ws[32 * 32];
    __shared__ float xs[8 * 32];
    __shared__ float bs[32];
    int tid = threadIdx.x;
    for (int i = tid; i < 1024; i += 256) Ws[i] = W1[i];
    if (tid < 32) bs[tid] = b1[tid];
    xs[tid] = x[blockIdx.x * 256 + tid];
    __syncthreads();
    int r = tid >> 5, c = tid & 31;
    float acc = bs[c];
#pragma unroll
    for (int k = 0; k < 32; ++k) acc += xs[r * 32 + k] * Ws[k * 32 + c];
    // row = blk*8 + r; out idx = row*32 + c = blk*256 + tid
    h[blockIdx.x * 256 + tid] = acc;
}

// ---------------------------------------------------------------------------
// Kernel 2: temporal mix + combine.
//   w[t,c] = sum_u At[t,u] * h[u,c]   (c in [0,4096) = n*32+f, per batch)
//   up[t,c] = s1*h + s3*w ;  pp[t,c] = s0*h + s2*w
// grid = BATCH * 64 (64 column-chunks of 64), block = 64 threads (1 wave)
// ---------------------------------------------------------------------------
__global__ __launch_bounds__(64) void k_temporal(
    const float* __restrict__ h, const float* __restrict__ At,
    const float* __restrict__ s, float* __restrict__ up, float* __restrict__ pp)
{
    __shared__ float At_s[64 * 64];
    int b = blockIdx.x >> 6;
    int chunk = blockIdx.x & 63;
    int tid = threadIdx.x;
    for (int i = tid; i < 4096; i += 64) At_s[i] = At[i];
    __syncthreads();

    int c = chunk * 64 + tid;
    const float* hb = h + b * HSTATE;
    float acc[64];
#pragma unroll
    for (int t = 0; t < 64; ++t) acc[t] = 0.f;
    for (int u = 0; u < 64; ++u) {
        float hv = hb[u * 4096 + c];
#pragma unroll
        for (int t = 0; t < 64; ++t) acc[t] += At_s[t * 64 + u] * hv;
    }
    float s0 = s[0], s1 = s[1], s2 = s[2], s3 = s[3];
    float* ub = up + b * HSTATE;
    float* pb = pp + b * HSTATE;
#pragma unroll
    for (int t = 0; t < 64; ++t) {
        float hv = hb[t * 4096 + c];
        float w  = acc[t];
        ub[t * 4096 + c] = s1 * hv + s3 * w;
        pb[t * 4096 + c] = s0 * hv + s2 * w;
    }
}

// ---------------------------------------------------------------------------
// Kernel 3: spatial mix + graph filter + tanh, per (b,t) tile.
//   Ah = pp[b,t] + A_s @ up[b,t]          ([128 x 32])
//   h  = tanh(Ah @ Hsum[l])               (Hsum = sum_k H[l,k], [32 x 32])
// grid = BATCH*T = 128 blocks, block = 256 threads
// ---------------------------------------------------------------------------
__global__ __launch_bounds__(256) void k_spatial_filter(
    const float* __restrict__ up, const float* __restrict__ pp,
    const float* __restrict__ As, const float* __restrict__ H,
    int layer, float* __restrict__ h)
{
    __shared__ float As_s[128 * 128];   // 64 KB
    __shared__ float u_s[128 * 32];     // 16 KB
    __shared__ float Ah_s[128 * 32];    // 16 KB
    __shared__ float Hs[32 * 32];       //  4 KB
    int bt = blockIdx.x;
    int tid = threadIdx.x;

    const float* Hl = H + layer * (KORD * 1024);
    for (int i = tid; i < 1024; i += 256)
        Hs[i] = Hl[i] + Hl[1024 + i] + Hl[2048 + i] + Hl[3072 + i];
    const float* ub = up + bt * 4096;
    for (int i = tid; i < 4096; i += 256) u_s[i] = ub[i];
    for (int i = tid; i < 16384; i += 256) As_s[i] = As[i];
    __syncthreads();

    int f = tid & 31;
    int m0 = tid >> 5;                 // 8 row-groups
    const float* pb = pp + bt * 4096;
#pragma unroll
    for (int j = 0; j < 16; ++j) {
        int m = m0 + j * 8;
        float acc = pb[m * 32 + f];
        const float* Arow = &As_s[m * 128];
#pragma unroll 8
        for (int n = 0; n < 128; ++n) acc += Arow[n] * u_s[n * 32 + f];
        Ah_s[m * 32 + f] = acc;
    }
    __syncthreads();

    float* hb = h + bt * 4096;
#pragma unroll
    for (int j = 0; j < 16; ++j) {
        int m = m0 + j * 8;
        float acc = 0.f;
#pragma unroll
        for (int k = 0; k < 32; ++k) acc += Ah_s[m * 32 + k] * Hs[k * 32 + f];
        hb[m * 32 + f] = tanhf(acc);
    }
}

// ---------------------------------------------------------------------------
// Kernel 4: out = h @ W2 + b2.  [16384 x 32] @ [32 x 16]
// block = 256 -> 16 rows/block; grid = 1024
// ---------------------------------------------------------------------------
__global__ __launch_bounds__(256) void k_proj_out(
    const float* __restrict__ h, const float* __restrict__ W2,
    const float* __restrict__ b2, float* __restrict__ out)
{
    __shared__ float Ws[32 * 16];
    __shared__ float hs[16 * 32];
    __shared__ float bs[16];
    int tid = threadIdx.x;
    // W2 has 512 elements; block is 256 threads -> load BOTH halves (round-1 bug fix)
    Ws[tid]       = W2[tid];
    Ws[tid + 256] = W2[tid + 256];
    if (tid < 16) bs[tid] = b2[tid];
    hs[tid]       = h[blockIdx.x * 512 + tid];
    hs[tid + 256] = h[blockIdx.x * 512 + tid + 256];
    __syncthreads();
    int r = tid >> 4, c = tid & 15;
    float acc = bs[c];
#pragma unroll
    for (int k = 0; k < 32; ++k) acc += hs[r * 32 + k] * Ws[k * 16 + c];
    // row = blk*16 + r; out idx = row*16 + c = blk*256 + tid
    out[blockIdx.x * 256 + tid] = acc;
}

// ---------------------------------------------------------------------------
extern "C" void kernel_launch(void* const* d_in, const int* in_sizes, int n_in,
                              void* d_out, int out_size, void* d_ws, size_t ws_size,
                              hipStream_t stream)
{
    const float* x   = (const float*)d_in[0];
    const float* At  = (const float*)d_in[1];
    const float* As  = (const float*)d_in[2];
    const float* s   = (const float*)d_in[3];
    const float* H   = (const float*)d_in[4];
    const float* W1  = (const float*)d_in[5];
    const float* b1  = (const float*)d_in[6];
    const float* W2  = (const float*)d_in[7];
    const float* b2  = (const float*)d_in[8];
    float* out = (float*)d_out;

    float* h  = (float*)d_ws;                 // BATCH * HSTATE
    float* up = h  + BATCH * HSTATE;
    float* pp = up + BATCH * HSTATE;

    k_proj_in<<<(BATCH * M_TOT * HIDW) / 256, 256, 0, stream>>>(x, W1, b1, h);
    for (int l = 0; l < NLAYER; ++l) {
        k_temporal<<<BATCH * 64, 64, 0, stream>>>(h, At, s, up, pp);
        k_spatial_filter<<<BATCH * T_DIM, 256, 0, stream>>>(up, pp, As, H, l, h);
    }
    k_proj_out<<<(BATCH * M_TOT) / 16, 256, 0, stream>>>(h, W2, b2, out);
}

// Round 3
// 55.647 us; speedup vs baseline: 4.4474x; 4.4474x over previous
//
#include <hip/hip_runtime.h>

// Problem constants (from reference)
#define T_DIM   64
#define N_DIM   128
#define M_TOT   (T_DIM * N_DIM)     // 8192
#define BATCH   2
#define F_IN    32
#define HIDW    32
#define F_OUT   16
#define NLAYER  2
#define KORD    4

#define HSTATE  (M_TOT * HIDW)      // 262144 floats per batch

// ---------------------------------------------------------------------------
// Kernel 1: h = x @ W1 + b1.  [16384 x 32] @ [32 x 32]
// ---------------------------------------------------------------------------
__global__ __launch_bounds__(256) void k_proj_in(
    const float* __restrict__ x, const float* __restrict__ W1,
    const float* __restrict__ b1, float* __restrict__ h)
{
    __shared__ float Ws[32 * 32];
    __shared__ float xs[8 * 32];
    __shared__ float bs[32];
    int tid = threadIdx.x;
    for (int i = tid; i < 1024; i += 256) Ws[i] = W1[i];
    if (tid < 32) bs[tid] = b1[tid];
    xs[tid] = x[blockIdx.x * 256 + tid];
    __syncthreads();
    int r = tid >> 5, c = tid & 31;
    float acc = bs[c];
#pragma unroll
    for (int k = 0; k < 32; ++k) acc += xs[r * 32 + k] * Ws[k * 32 + c];
    h[blockIdx.x * 256 + tid] = acc;
}

// ---------------------------------------------------------------------------
// Fused layer kernel: one block per (b,t), 1024 threads (16 waves).
//   Phase 1 (temporal): w[c] = sum_u At[t,u]*h[u,c];
//                       up = s1*h + s3*w (transposed to LDS), pp = s0*h + s2*w
//   Phase 2 (spatial):  Ah[m,f] = pp[m,f] + sum_n As[m,n]*up[n,f]
//   Phase 3 (filter):   h_out[m,f] = tanh(sum_k Ah[m,k]*Hsum[k,f])
// ---------------------------------------------------------------------------
__global__ __launch_bounds__(1024) void k_layer(
    const float* __restrict__ h_in, const float* __restrict__ At,
    const float* __restrict__ As, const float* __restrict__ s,
    const float* __restrict__ H, int layer, float* __restrict__ h_out)
{
    __shared__ float As_s[128 * 128];   // 64 KB
    __shared__ float up_t[32 * 132];    // transposed [f][n], pad 4 -> 16.5 KB
    __shared__ float pa_s[128 * 32];    // pp, then Ah in-place      16 KB
    __shared__ float Hs[1024];          // sum_k H[l,k]               4 KB

    const int tid = threadIdx.x;
    const int bt  = blockIdx.x;          // b*64 + t
    const int b   = bt >> 6, t = bt & 63;

    // --- stage As (broadcast-consumed in phase 2) and Hsum; overlaps phase 1 ---
    {
        const float4* src = (const float4*)As;
        float4* dst = (float4*)As_s;
#pragma unroll
        for (int i = 0; i < 4; ++i) dst[tid + 1024 * i] = src[tid + 1024 * i];
    }
    {
        const float* Hl = H + layer * (KORD * 1024);
        Hs[tid & 1023] = Hl[tid & 1023] + Hl[1024 + (tid & 1023)]
                       + Hl[2048 + (tid & 1023)] + Hl[3072 + (tid & 1023)];
    }

    // --- phase 1: temporal mix for 4 columns per thread ---
    const float* hb = h_in + b * HSTATE;          // [64][4096]
    const int c0 = tid * 4;
    float w0 = 0.f, w1 = 0.f, w2 = 0.f, w3 = 0.f;
#pragma unroll 8
    for (int u = 0; u < 64; ++u) {
        float a = At[t * 64 + u];                 // wave-uniform -> s_load
        float4 v = *(const float4*)(hb + u * 4096 + c0);
        w0 += a * v.x; w1 += a * v.y; w2 += a * v.z; w3 += a * v.w;
    }
    float4 hv = *(const float4*)(hb + t * 4096 + c0);
    const float s0v = s[0], s1v = s[1], s2v = s[2], s3v = s[3];
    const int f0 = c0 & 31, n0 = c0 >> 5;         // c = n*32 + f
    up_t[(f0 + 0) * 132 + n0] = s1v * hv.x + s3v * w0;
    up_t[(f0 + 1) * 132 + n0] = s1v * hv.y + s3v * w1;
    up_t[(f0 + 2) * 132 + n0] = s1v * hv.z + s3v * w2;
    up_t[(f0 + 3) * 132 + n0] = s1v * hv.w + s3v * w3;
    float4 pp;
    pp.x = s0v * hv.x + s2v * w0;
    pp.y = s0v * hv.y + s2v * w1;
    pp.z = s0v * hv.z + s2v * w2;
    pp.w = s0v * hv.w + s2v * w3;
    *(float4*)(pa_s + c0) = pp;
    __syncthreads();

    // --- phase 2: spatial mix.  thread (f, mg) owns m = mg + 32j, j<4 ---
    const int f  = tid & 31;
    const int mg = tid >> 5;                      // 0..31
    float acc0 = pa_s[(mg     ) * 32 + f];
    float acc1 = pa_s[(mg + 32) * 32 + f];
    float acc2 = pa_s[(mg + 64) * 32 + f];
    float acc3 = pa_s[(mg + 96) * 32 + f];
    for (int n = 0; n < 128; n += 4) {
        float4 u4 = *(const float4*)(up_t + f * 132 + n);
        float4 a0 = *(const float4*)(As_s + (mg     ) * 128 + n);
        float4 a1 = *(const float4*)(As_s + (mg + 32) * 128 + n);
        float4 a2 = *(const float4*)(As_s + (mg + 64) * 128 + n);
        float4 a3 = *(const float4*)(As_s + (mg + 96) * 128 + n);
        acc0 += a0.x * u4.x + a0.y * u4.y + a0.z * u4.z + a0.w * u4.w;
        acc1 += a1.x * u4.x + a1.y * u4.y + a1.z * u4.z + a1.w * u4.w;
        acc2 += a2.x * u4.x + a2.y * u4.y + a2.z * u4.z + a2.w * u4.w;
        acc3 += a3.x * u4.x + a3.y * u4.y + a3.z * u4.z + a3.w * u4.w;
    }
    // write Ah in-place (each slot's only reader is this thread)
    pa_s[(mg     ) * 32 + f] = acc0;
    pa_s[(mg + 32) * 32 + f] = acc1;
    pa_s[(mg + 64) * 32 + f] = acc2;
    pa_s[(mg + 96) * 32 + f] = acc3;
    __syncthreads();

    // --- phase 3: h_out = tanh(Ah @ Hsum) ---
    float* ho = h_out + bt * 4096;
#pragma unroll
    for (int j = 0; j < 4; ++j) {
        const int m = mg + 32 * j;
        float acc = 0.f;
#pragma unroll
        for (int k = 0; k < 32; k += 4) {
            float4 a4 = *(const float4*)(pa_s + m * 32 + k);   // broadcast
            acc += a4.x * Hs[(k + 0) * 32 + f] + a4.y * Hs[(k + 1) * 32 + f]
                 + a4.z * Hs[(k + 2) * 32 + f] + a4.w * Hs[(k + 3) * 32 + f];
        }
        ho[m * 32 + f] = tanhf(acc);
    }
}

// ---------------------------------------------------------------------------
// Kernel 4: out = h @ W2 + b2.  [16384 x 32] @ [32 x 16]
// ---------------------------------------------------------------------------
__global__ __launch_bounds__(256) void k_proj_out(
    const float* __restrict__ h, const float* __restrict__ W2,
    const float* __restrict__ b2, float* __restrict__ out)
{
    __shared__ float Ws[32 * 16];
    __shared__ float hs[16 * 32];
    __shared__ float bs[16];
    int tid = threadIdx.x;
    Ws[tid]       = W2[tid];
    Ws[tid + 256] = W2[tid + 256];
    if (tid < 16) bs[tid] = b2[tid];
    hs[tid]       = h[blockIdx.x * 512 + tid];
    hs[tid + 256] = h[blockIdx.x * 512 + tid + 256];
    __syncthreads();
    int r = tid >> 4, c = tid & 15;
    float acc = bs[c];
#pragma unroll
    for (int k = 0; k < 32; ++k) acc += hs[r * 32 + k] * Ws[k * 16 + c];
    out[blockIdx.x * 256 + tid] = acc;
}

// ---------------------------------------------------------------------------
extern "C" void kernel_launch(void* const* d_in, const int* in_sizes, int n_in,
                              void* d_out, int out_size, void* d_ws, size_t ws_size,
                              hipStream_t stream)
{
    const float* x   = (const float*)d_in[0];
    const float* At  = (const float*)d_in[1];
    const float* As  = (const float*)d_in[2];
    const float* s   = (const float*)d_in[3];
    const float* H   = (const float*)d_in[4];
    const float* W1  = (const float*)d_in[5];
    const float* b1  = (const float*)d_in[6];
    const float* W2  = (const float*)d_in[7];
    const float* b2  = (const float*)d_in[8];
    float* out = (float*)d_out;

    float* hA = (float*)d_ws;                 // BATCH * HSTATE
    float* hB = hA + BATCH * HSTATE;          // ping-pong (blocks read all of h_in)

    k_proj_in<<<(BATCH * M_TOT * HIDW) / 256, 256, 0, stream>>>(x, W1, b1, hA);
    k_layer<<<BATCH * T_DIM, 1024, 0, stream>>>(hA, At, As, s, H, 0, hB);
    k_layer<<<BATCH * T_DIM, 1024, 0, stream>>>(hB, At, As, s, H, 1, hA);
    k_proj_out<<<(BATCH * M_TOT) / 16, 256, 0, stream>>>(hA, W2, b2, out);
}

// Round 4
// 33.145 us; speedup vs baseline: 7.4667x; 1.6789x over previous
//
#include <hip/hip_runtime.h>

#define T_DIM 64
#define N_DIM 128
#define BATCH 2
#define F_IN  32
#define HIDW  32
#define F_OUT 16
#define KORD  4

// Layouts:
//   x     : [B][T*N][F_IN]            (given, m = t*128+n)
//   up/pp : [B][T][N][HIDW]           (workspace)
//   h     : [B][N][T][HIDW]           (n-major -> contiguous reads in k_temporal<false>)
//   out   : [B][T*N][F_OUT]

// ---------------------------------------------------------------------------
// A kernel: (optional input projection) + temporal mix.
// grid = B*N = 256 blocks, 512 threads = 8 waves.
//   wave fg = tid>>6  -> f-chunk [fg*4, fg*4+4)
//   lane t  = tid&63  -> time step
//   w[t,f] = sum_u At[t,u] * h[u,f];  up = s1*h + s3*w;  pp = s0*h + s2*w
// ---------------------------------------------------------------------------
template<bool PROJ>
__global__ __launch_bounds__(512) void k_temporal(
    const float* __restrict__ src,     // PROJ ? x : h (n-major)
    const float* __restrict__ At,
    const float* __restrict__ W1, const float* __restrict__ b1,
    const float* __restrict__ s,
    float* __restrict__ up, float* __restrict__ pp)
{
    __shared__ float At_s[64 * 65];    // pad 65: read bank (t+u)%32, 2-way = free
    __shared__ float h_loc[64 * 36];   // pad 36: b128-aligned rows, broadcast reads
    __shared__ float xs[64 * 33];      // pad 33: read bank (t+k)%32 (PROJ only)
    __shared__ float W1s[32 * 32];     // broadcast reads (PROJ only)

    const int tid = threadIdx.x;
    const int b   = blockIdx.x >> 7;
    const int n   = blockIdx.x & 127;
    const int fg  = tid >> 6;
    const int t   = tid & 63;

    // hoist uniform scalar loads to hide latency under staging
    const float s0v = s[0], s1v = s[1], s2v = s[2], s3v = s[3];

    // stage At [64][64] -> pad 65 (coalesced gmem, conflict-free LDS writes)
#pragma unroll
    for (int i = 0; i < 8; ++i) {
        int p = tid + 512 * i;
        At_s[(p >> 6) * 65 + (p & 63)] = At[p];
    }
    if (PROJ) {
        // stage x rows x[b, t*128+n, :] -> xs[64][33]
        {
            int tt = tid >> 3, c4 = tid & 7;
            float4 v = *(const float4*)(src + ((size_t)(b * 8192 + tt * 128 + n)) * 32 + c4 * 4);
            float* dst = &xs[tt * 33 + c4 * 4];
            dst[0] = v.x; dst[1] = v.y; dst[2] = v.z; dst[3] = v.w;
        }
        if (tid < 256) ((float4*)W1s)[tid] = ((const float4*)W1)[tid];
    } else {
        // stage h[b, n, :, :] (contiguous 8KB) -> h_loc[64][36]
        int tt = tid >> 3, c4 = tid & 7;
        float4 v = *(const float4*)(src + ((size_t)(b * 128 + n)) * 2048 + tt * 32 + c4 * 4);
        *(float4*)&h_loc[tt * 36 + c4 * 4] = v;
    }
    __syncthreads();

    float h0, h1, h2, h3;
    if (PROJ) {
        float4 bv = *(const float4*)(b1 + fg * 4);
        h0 = bv.x; h1 = bv.y; h2 = bv.z; h3 = bv.w;
#pragma unroll 8
        for (int k = 0; k < 32; ++k) {
            float xv = xs[t * 33 + k];                       // 2-way, free
            float4 wv = *(const float4*)(W1s + k * 32 + fg * 4); // broadcast
            h0 += xv * wv.x; h1 += xv * wv.y; h2 += xv * wv.z; h3 += xv * wv.w;
        }
        float4 hv; hv.x = h0; hv.y = h1; hv.z = h2; hv.w = h3;
        *(float4*)&h_loc[t * 36 + fg * 4] = hv;
        __syncthreads();
    } else {
        float4 hv = *(const float4*)&h_loc[t * 36 + fg * 4];
        h0 = hv.x; h1 = hv.y; h2 = hv.z; h3 = hv.w;
    }

    // temporal mix
    float w0 = 0.f, w1 = 0.f, w2 = 0.f, w3 = 0.f;
#pragma unroll 4
    for (int u = 0; u < 64; ++u) {
        float a = At_s[t * 65 + u];                           // 2-way, free
        float4 hv = *(const float4*)&h_loc[u * 36 + fg * 4];  // broadcast
        w0 += a * hv.x; w1 += a * hv.y; w2 += a * hv.z; w3 += a * hv.w;
    }
    float4 u4, p4;
    u4.x = s1v * h0 + s3v * w0;  p4.x = s0v * h0 + s2v * w0;
    u4.y = s1v * h1 + s3v * w1;  p4.y = s0v * h1 + s2v * w1;
    u4.z = s1v * h2 + s3v * w2;  p4.z = s0v * h2 + s2v * w2;
    u4.w = s1v * h3 + s3v * w3;  p4.w = s0v * h3 + s2v * w3;
    size_t base = ((size_t)((b * 64 + t) * 128 + n)) * 32 + fg * 4;
    *(float4*)(up + base) = u4;
    *(float4*)(pp + base) = p4;
}

// ---------------------------------------------------------------------------
// B kernel: spatial mix + graph filter (+ fused output projection if LAST).
// grid = B*T*2 = 256 blocks, 512 threads = 8 waves.
//   wave fg = tid>>6 -> f-chunk [fg*4, fg*4+4);  lane m = tid&63 -> local row
//   Ah[m,f] = pp[m,f] + sum_n As[mh*64+m, n] * up[n,f]
//   T[m,f]  = tanh(sum_k Ah[m,k] * Hsum[k,f])
//   LAST: out[m,fo] = sum_k T[m,k]*W2[k,fo] + b2[fo]
// ---------------------------------------------------------------------------
template<bool LAST>
__global__ __launch_bounds__(512) void k_spatial(
    const float* __restrict__ up, const float* __restrict__ pp,
    const float* __restrict__ As, const float* __restrict__ H, int layer,
    const float* __restrict__ W2, const float* __restrict__ b2,
    float* __restrict__ hout, float* __restrict__ out)
{
    __shared__ float As_s[64 * 128];   // XOR-swizzled 16B groups: g' = g ^ (row&31)
    __shared__ float up_s[128 * 32];   // broadcast-consumed
    __shared__ float Ah_s[64 * 33];    // pad 33: lane-distinct rw conflict-free
    __shared__ float T_s[64 * 33];     // LAST only
    __shared__ float Hs[32 * 32];
    __shared__ float W2s[32 * 16];     // LAST only

    const int tid = threadIdx.x;
    const int b   = blockIdx.x >> 7;
    const int t   = (blockIdx.x >> 1) & 63;
    const int mh  = blockIdx.x & 1;
    const int fg  = tid >> 6;
    const int m   = tid & 63;

    // stage As half-tile [64][128], swizzled (write & read both conflict-free)
#pragma unroll
    for (int i = 0; i < 4; ++i) {
        int p = tid + 512 * i;
        int r = p >> 5, g = p & 31;
        float4 v = *(const float4*)(As + ((size_t)(mh * 64 + r)) * 128 + g * 4);
        *(float4*)&As_s[r * 128 + ((g ^ (r & 31)) << 2)] = v;
    }
    // stage up tile [128][32] (linear, coalesced)
    {
        const float4* srcu = (const float4*)(up + ((size_t)(b * 64 + t)) * 4096);
        float4* du = (float4*)up_s;
        du[tid]       = srcu[tid];
        du[tid + 512] = srcu[tid + 512];
    }
    // Hsum = sum_k H[l,k]
    {
        const float* Hl = H + layer * 4096;
        for (int i = tid; i < 1024; i += 512)
            Hs[i] = Hl[i] + Hl[1024 + i] + Hl[2048 + i] + Hl[3072 + i];
    }
    if (LAST) {
        if (tid < 128) ((float4*)W2s)[tid] = ((const float4*)W2)[tid];
    }
    // acc init from pp (gmem, hides under staging)
    float4 pv = *(const float4*)(pp + (((size_t)(b * 64 + t)) * 128 + mh * 64 + m) * 32 + fg * 4);
    float a0 = pv.x, a1 = pv.y, a2 = pv.z, a3 = pv.w;
    __syncthreads();

    // phase 2: spatial mix; As lane-distinct b128 (swizzle -> conflict-free),
    // up broadcast b128.
#pragma unroll 4
    for (int cu = 0; cu < 32; ++cu) {
        float4 av = *(const float4*)&As_s[m * 128 + ((cu ^ (m & 31)) << 2)];
        float4 u0 = *(const float4*)&up_s[(cu * 4 + 0) * 32 + fg * 4];
        float4 u1 = *(const float4*)&up_s[(cu * 4 + 1) * 32 + fg * 4];
        float4 u2 = *(const float4*)&up_s[(cu * 4 + 2) * 32 + fg * 4];
        float4 u3 = *(const float4*)&up_s[(cu * 4 + 3) * 32 + fg * 4];
        a0 += av.x * u0.x + av.y * u1.x + av.z * u2.x + av.w * u3.x;
        a1 += av.x * u0.y + av.y * u1.y + av.z * u2.y + av.w * u3.y;
        a2 += av.x * u0.z + av.y * u1.z + av.z * u2.z + av.w * u3.z;
        a3 += av.x * u0.w + av.y * u1.w + av.z * u2.w + av.w * u3.w;
    }
    Ah_s[m * 33 + fg * 4 + 0] = a0;
    Ah_s[m * 33 + fg * 4 + 1] = a1;
    Ah_s[m * 33 + fg * 4 + 2] = a2;
    Ah_s[m * 33 + fg * 4 + 3] = a3;
    __syncthreads();

    // phase 3: graph filter + tanh
    float c0 = 0.f, c1 = 0.f, c2 = 0.f, c3 = 0.f;
#pragma unroll 8
    for (int k = 0; k < 32; ++k) {
        float av = Ah_s[m * 33 + k];                      // 2-way, free
        float4 hv = *(const float4*)&Hs[k * 32 + fg * 4]; // broadcast
        c0 += av * hv.x; c1 += av * hv.y; c2 += av * hv.z; c3 += av * hv.w;
    }
    c0 = tanhf(c0); c1 = tanhf(c1); c2 = tanhf(c2); c3 = tanhf(c3);

    if (!LAST) {
        float4 o; o.x = c0; o.y = c1; o.z = c2; o.w = c3;
        // h stored n-major: [b][nglob][t][f]
        *(float4*)(hout + (((size_t)(b * 128 + mh * 64 + m)) * 64 + t) * 32 + fg * 4) = o;
    } else {
        T_s[m * 33 + fg * 4 + 0] = c0;
        T_s[m * 33 + fg * 4 + 1] = c1;
        T_s[m * 33 + fg * 4 + 2] = c2;
        T_s[m * 33 + fg * 4 + 3] = c3;
        __syncthreads();
        // fused output projection: wave fg covers fo = {fg*2, fg*2+1}
        float o0 = b2[fg * 2], o1 = b2[fg * 2 + 1];
#pragma unroll 8
        for (int k = 0; k < 32; ++k) {
            float tv = T_s[m * 33 + k];                   // 2-way, free
            o0 += tv * W2s[k * 16 + fg * 2];              // broadcast
            o1 += tv * W2s[k * 16 + fg * 2 + 1];
        }
        float2 o; o.x = o0; o.y = o1;
        *(float2*)(out + (((size_t)(b * 64 + t)) * 128 + mh * 64 + m) * 16 + fg * 2) = o;
    }
}

// ---------------------------------------------------------------------------
extern "C" void kernel_launch(void* const* d_in, const int* in_sizes, int n_in,
                              void* d_out, int out_size, void* d_ws, size_t ws_size,
                              hipStream_t stream)
{
    const float* x   = (const float*)d_in[0];
    const float* At  = (const float*)d_in[1];
    const float* As  = (const float*)d_in[2];
    const float* s   = (const float*)d_in[3];
    const float* H   = (const float*)d_in[4];
    const float* W1  = (const float*)d_in[5];
    const float* b1  = (const float*)d_in[6];
    const float* W2  = (const float*)d_in[7];
    const float* b2  = (const float*)d_in[8];
    float* out = (float*)d_out;

    const size_t SZ = (size_t)BATCH * T_DIM * N_DIM * HIDW;  // 524288 floats
    float* up = (float*)d_ws;
    float* pp = up + SZ;
    float* h  = pp + SZ;

    k_temporal<true ><<<BATCH * N_DIM, 512, 0, stream>>>(x, At, W1, b1, s, up, pp);
    k_spatial <false><<<BATCH * T_DIM * 2, 512, 0, stream>>>(up, pp, As, H, 0, W2, b2, h, out);
    k_temporal<false><<<BATCH * N_DIM, 512, 0, stream>>>(h, At, W1, b1, s, up, pp);
    k_spatial <true ><<<BATCH * T_DIM * 2, 512, 0, stream>>>(up, pp, As, H, 1, W2, b2, h, out);
}